// Round 1
// baseline (305.413 us; speedup 1.0000x reference)
//
#include <hip/hip_runtime.h>
#include <stdint.h>

typedef __bf16 bf16x8 __attribute__((ext_vector_type(8)));
typedef float  f32x4  __attribute__((ext_vector_type(4)));
typedef unsigned short u16x4 __attribute__((ext_vector_type(4)));

// ---- geometry ----
// rows per block = 128, threads = 512 (8 waves, wave grid 2M x 4N)
// GEMM1: K=288 (108 hsum + 172 x2 + 8 zero pad), N=512, 9 k-tiles of 32
// GEMM2: K=512, N=192 (172 + 20 zero pad), 16 k-tiles of 32
#define XS_B   592      // x LDS row stride bytes (296 bf16)
#define HS_B   1040     // h LDS row stride bytes (520 bf16)
#define B1_OFF 75776    // x buf = [0, 75776)
#define B1_SZ  32768    // B1 tile [512][32] bf16, double buffered
#define B2_OFF 133120   // h buf = [0, 133120)
#define B2_SZ  12288    // B2 tile [192][32] bf16, double buffered
#define LDS_SZ 157696

// workspace offsets (bytes)
#define WS_FC1T   0         // bf16 [512][288]  (fc1_eff transposed, K-padded)
#define WS_FC2T   294912    // bf16 [192][512]  (fc2_w transposed, N-padded)
#define WS_BIAS   491520    // f32  [512]       (folded bias)

__device__ __forceinline__ unsigned short f2bf(float f) {
  union { float f; unsigned u; } c; c.f = f;
  unsigned u = c.u;
  u += 0x7FFFu + ((u >> 16) & 1u);   // RTNE
  return (unsigned short)(u >> 16);
}

__device__ __forceinline__ void g2l16(const void* g, void* l) {
  __builtin_amdgcn_global_load_lds(
      (const __attribute__((address_space(1))) void*)g,
      (__attribute__((address_space(3))) void*)l, 16, 0, 0);
}

// ---------------- prep: fold W2 into fc1_w, transpose + bf16 ----------------
__global__ void POLAR_prep_fc1(const float* __restrict__ W2,
                               const float* __restrict__ fc1_w,
                               const float* __restrict__ fc1_b,
                               const float* __restrict__ b2,
                               unsigned short* __restrict__ fc1t,
                               float* __restrict__ bias_eff) {
  int n = blockIdx.x;      // 0..511
  int k = threadIdx.x;     // 0..287
  float v = 0.f;
  if (k < 108) {           // folded: sum_f W2[k,f] * fc1_w[f,n]
    for (int f = 0; f < 108; ++f) v += W2[k*108 + f] * fc1_w[f*512 + n];
  } else if (k < 280) {    // x2 part of fc1_w
    v = fc1_w[k*512 + n];
  }
  fc1t[n*288 + k] = f2bf(v);
  if (k == 0) {
    float bb = fc1_b[n];
    for (int f = 0; f < 108; ++f) bb += 2.f * b2[f] * fc1_w[f*512 + n];
    bias_eff[n] = bb;
  }
}

__global__ void POLAR_prep_fc2(const float* __restrict__ fc2_w,
                               unsigned short* __restrict__ fc2t) {
  int n = blockIdx.x;     // 0..191
  int k = threadIdx.x;    // 0..511
  float v = (n < 172) ? fc2_w[k*172 + n] : 0.f;
  fc2t[n*512 + k] = f2bf(v);
}

// ---------------- fused main kernel ----------------
__global__ __launch_bounds__(512, 2) void POLAR_fused(
    const float* __restrict__ emb, const int* __restrict__ idx,
    const float* __restrict__ W1, const float* __restrict__ b1,
    const float* __restrict__ x2,
    const unsigned short* __restrict__ fc1t,   // bf16 [512][288]
    const float* __restrict__ bias_eff,        // [512]
    const unsigned short* __restrict__ fc2t,   // bf16 [192][512]
    const float* __restrict__ fc2b,            // [172]
    float* __restrict__ out)
{
  __shared__ __attribute__((aligned(16))) char smem[LDS_SZ];
  const int tid  = threadIdx.x;
  const int lane = tid & 63;
  const int w    = tid >> 6;
  const int wm   = w >> 2;       // 0..1 : rows wm*64 + 4 frags
  const int wn   = w & 3;        // 0..3 : G1 cols wn*128 (8 frags), G2 cols wn*48 (3 frags)
  const int blk  = blockIdx.x;
  const int l15  = lane & 15;
  const int l4   = lane >> 4;    // k-slot 0..3

  // ---- stage B1 tile 0 (async, overlaps PE phase) ----
  {
    int nr = lane >> 2, slds = lane & 3;
    #pragma unroll
    for (int j = 0; j < 4; ++j) {
      int c = w * 4 + j;
      int n = c * 16 + nr;
      int sg = slds ^ ((n >> 1) & 3);               // XOR slot swizzle (involution)
      g2l16((const char*)fc1t + n * 576 + sg * 16, smem + B1_OFF + c * 1024);
    }
  }

  // ---- PE phase: hsum -> x cols 0..107 ----
  {
    int r  = tid >> 2;        // 0..127 (4 threads/row)
    int li = tid & 3;         // 27 enc outputs each
    size_t g = (size_t)blk * 128 + r;
    int key = idx[g];
    const float* ep = emb + (size_t)key * 8;
    f32x4 e0 = *(const f32x4*)ep;
    f32x4 e1 = *(const f32x4*)(ep + 4);
    int ebase = li * 27;
    for (int t = 0; t < 27; ++t) {
      int e = ebase + t;
      float w0 = W1[e], w1v = W1[108 + e], w2v = W1[216 + e], w3v = W1[324 + e];
      float bb = b1[e];
      float a0 = fmaxf(e0.x*w0 + e0.y*w1v + e0.z*w2v + e0.w*w3v + bb, 0.f);
      float a1 = fmaxf(e1.x*w0 + e1.y*w1v + e1.z*w2v + e1.w*w3v + bb, 0.f);
      *(unsigned short*)(smem + r * XS_B + e * 2) = f2bf(a0 + a1);
    }
  }

  // ---- x2 -> x cols 108..279 (bf16), zero pad 280..287 ----
  {
    const f32x4* x2v = (const f32x4*)(x2 + (size_t)blk * 128 * 172);
    for (int t = tid; t < 128 * 43; t += 512) {
      int r = t / 43, c4 = t - r * 43;
      f32x4 v = x2v[r * 43 + c4];
      u16x4 s; s.x = f2bf(v.x); s.y = f2bf(v.y); s.z = f2bf(v.z); s.w = f2bf(v.w);
      *(u16x4*)(smem + r * XS_B + 216 + c4 * 8) = s;
    }
    if (tid < 128) {
      u16x4 z = (u16x4){0,0,0,0};
      *(u16x4*)(smem + tid * XS_B + 560) = z;
      *(u16x4*)(smem + tid * XS_B + 568) = z;
    }
  }
  __syncthreads();   // x ready; B1 tile0 drained (vmcnt0 at barrier)

  // ---- GEMM1: [128x288] x [288x512] -> acc[4][8] ----
  f32x4 acc[4][8];
  #pragma unroll
  for (int i = 0; i < 4; ++i)
    #pragma unroll
    for (int j = 0; j < 8; ++j)
      acc[i][j] = (f32x4){0.f, 0.f, 0.f, 0.f};

  #pragma unroll 1
  for (int kt = 0; kt < 9; ++kt) {
    int cur = kt & 1;
    if (kt < 8) {   // stage next k-tile into other buffer
      int nr = lane >> 2, slds = lane & 3;
      char* dst = smem + B1_OFF + (cur ^ 1) * B1_SZ;
      #pragma unroll
      for (int j = 0; j < 4; ++j) {
        int c = w * 4 + j;
        int n = c * 16 + nr;
        int sg = slds ^ ((n >> 1) & 3);
        g2l16((const char*)fc1t + n * 576 + (kt + 1) * 64 + sg * 16, dst + c * 1024);
      }
    }
    bf16x8 af[4];
    #pragma unroll
    for (int i = 0; i < 4; ++i) {
      int r = wm * 64 + i * 16 + l15;
      af[i] = *(const bf16x8*)(smem + r * XS_B + kt * 64 + l4 * 16);
    }
    const char* bb = smem + B1_OFF + cur * B1_SZ;
    bf16x8 bv[8];
    #pragma unroll
    for (int j = 0; j < 8; ++j) {
      int n = wn * 128 + j * 16 + l15;
      int so = l4 ^ ((n >> 1) & 3);
      bv[j] = *(const bf16x8*)(bb + n * 64 + so * 16);
    }
    #pragma unroll
    for (int i = 0; i < 4; ++i)
      #pragma unroll
      for (int j = 0; j < 8; ++j)
        acc[i][j] = __builtin_amdgcn_mfma_f32_16x16x32_bf16(af[i], bv[j], acc[i][j], 0, 0, 0);
    __syncthreads();
  }

  // ---- stage B2 tile 0 (region overlapped B1 buf1, now dead) ----
  {
    int nr = lane >> 2, slds = lane & 3;
    for (int c = w; c < 12; c += 8) {
      int n = c * 16 + nr;
      int sg = slds ^ ((n >> 1) & 3);
      g2l16((const char*)fc2t + n * 1024 + sg * 16, smem + B2_OFF + c * 1024);
    }
  }

  // ---- epilogue 1: h = relu(acc + bias_eff) -> LDS (overwrites x region) ----
  #pragma unroll
  for (int j = 0; j < 8; ++j) {
    int col = wn * 128 + j * 16 + l15;
    float be = bias_eff[col];
    #pragma unroll
    for (int i = 0; i < 4; ++i) {
      #pragma unroll
      for (int r2 = 0; r2 < 4; ++r2) {
        int row = wm * 64 + i * 16 + l4 * 4 + r2;   // C/D: col=lane&15, row=(lane>>4)*4+reg
        float v = fmaxf(acc[i][j][r2] + be, 0.f);
        *(unsigned short*)(smem + row * HS_B + col * 2) = f2bf(v);
      }
    }
  }
  __syncthreads();   // h ready; B2 tile0 drained

  // ---- GEMM2: [128x512] x [512x192] -> acc2[4][3] ----
  f32x4 acc2[4][3];
  #pragma unroll
  for (int i = 0; i < 4; ++i)
    #pragma unroll
    for (int j = 0; j < 3; ++j)
      acc2[i][j] = (f32x4){0.f, 0.f, 0.f, 0.f};

  #pragma unroll 1
  for (int kt = 0; kt < 16; ++kt) {
    int cur = kt & 1;
    if (kt < 15) {
      int nr = lane >> 2, slds = lane & 3;
      char* dst = smem + B2_OFF + (cur ^ 1) * B2_SZ;
      for (int c = w; c < 12; c += 8) {
        int n = c * 16 + nr;
        int sg = slds ^ ((n >> 1) & 3);
        g2l16((const char*)fc2t + n * 1024 + (kt + 1) * 64 + sg * 16, dst + c * 1024);
      }
    }
    bf16x8 af[4];
    #pragma unroll
    for (int i = 0; i < 4; ++i) {
      int r = wm * 64 + i * 16 + l15;
      af[i] = *(const bf16x8*)(smem + r * HS_B + kt * 64 + l4 * 16);
    }
    const char* bb2 = smem + B2_OFF + cur * B2_SZ;
    bf16x8 bv[3];
    #pragma unroll
    for (int j = 0; j < 3; ++j) {
      int n = wn * 48 + j * 16 + l15;
      int so = l4 ^ ((n >> 1) & 3);
      bv[j] = *(const bf16x8*)(bb2 + n * 64 + so * 16);
    }
    #pragma unroll
    for (int i = 0; i < 4; ++i)
      #pragma unroll
      for (int j = 0; j < 3; ++j)
        acc2[i][j] = __builtin_amdgcn_mfma_f32_16x16x32_bf16(af[i], bv[j], acc2[i][j], 0, 0, 0);
    __syncthreads();
  }

  // ---- epilogue 2: out = acc2 + fc2_b (mask cols >= 172) ----
  const size_t orow0 = (size_t)blk * 128;
  #pragma unroll
  for (int j = 0; j < 3; ++j) {
    int col = wn * 48 + j * 16 + l15;
    if (col < 172) {
      float bias = fc2b[col];
      #pragma unroll
      for (int i = 0; i < 4; ++i) {
        #pragma unroll
        for (int r2 = 0; r2 < 4; ++r2) {
          int row = wm * 64 + i * 16 + l4 * 4 + r2;
          out[(orow0 + row) * 172 + col] = acc2[i][j][r2] + bias;
        }
      }
    }
  }
}

extern "C" void kernel_launch(void* const* d_in, const int* in_sizes, int n_in,
                              void* d_out, int out_size, void* d_ws, size_t ws_size,
                              hipStream_t stream) {
  (void)in_sizes; (void)n_in; (void)out_size; (void)ws_size;
  const float* emb   = (const float*)d_in[0];
  const int*   idx   = (const int*)d_in[1];
  const float* W1    = (const float*)d_in[2];
  const float* b1    = (const float*)d_in[3];
  const float* W2    = (const float*)d_in[4];
  const float* b2    = (const float*)d_in[5];
  const float* x2    = (const float*)d_in[6];
  const float* fc1_w = (const float*)d_in[7];
  const float* fc1_b = (const float*)d_in[8];
  const float* fc2_w = (const float*)d_in[9];
  const float* fc2_b = (const float*)d_in[10];
  float* out = (float*)d_out;
  char* ws = (char*)d_ws;
  unsigned short* fc1t = (unsigned short*)(ws + WS_FC1T);
  unsigned short* fc2t = (unsigned short*)(ws + WS_FC2T);
  float* bias_eff = (float*)(ws + WS_BIAS);

  POLAR_prep_fc1<<<512, 288, 0, stream>>>(W2, fc1_w, fc1_b, b2, fc1t, bias_eff);
  POLAR_prep_fc2<<<192, 512, 0, stream>>>(fc2_w, fc2t);
  POLAR_fused<<<2048, 512, 0, stream>>>(emb, idx, W1, b1, x2, fc1t, bias_eff,
                                        fc2t, fc2_b, out);
}